// Round 13
// baseline (961.579 us; speedup 1.0000x reference)
//
#include <hip/hip_runtime.h>
#include <hip/hip_bf16.h>

#define HW2D 65536
#define NPIX 524288   // 8 * 65536
#define NB 8
#define PW 258
#define PP 66564      // 258*258
#define NSTEPS 16
#define RHH 2064      // 258*8  : HH plane stride (bytes)
#define RTT 4128      // 258*16 : TAIL half stride (bytes)
#define ROWB 8256     // 258*32 : full row stride (bytes), = 4*RHH = 2*RTT

typedef __hip_bfloat16 bf16;
typedef unsigned long long u64;
typedef __attribute__((ext_vector_type(8))) short short8;
typedef __attribute__((ext_vector_type(4))) float f32x4;

__device__ __forceinline__ unsigned short f2bfu(float v){
  bf16 h = __float2bfloat16(v); return *(unsigned short*)&h;
}
__device__ __forceinline__ float blo(unsigned int w){ return __uint_as_float(w<<16); }
__device__ __forceinline__ float bhi(unsigned int w){ return __uint_as_float(w & 0xffff0000u); }
// cheap odd tanh approx (max abs err ~0.055); hh reaches the wave state only
// through the 0.002*sigmoid gate, so downstream error is negligible
__device__ __forceinline__ float tanh_a(float z){
  return z*__builtin_amdgcn_rsqf(fmaf(z, z, 1.0f));
}
__device__ __forceinline__ float fast_sigmoid(float z){
  return 1.0f/(1.0f + __expf(-z));
}
__device__ __forceinline__ unsigned char f2fp8(float v){
  return (unsigned char)(__builtin_amdgcn_cvt_pk_fp8_f32(v, 0.f, 0, false) & 0xFF);
}
// record byte m <-> channel ch(m) = (m>>1) + (m&1)*16 ; plane g = bytes 8g..8g+7
__device__ __forceinline__ int chmap(int m){ return (m>>1) + (m&1)*16; }

// per-mt epilogue: hh_new = tanh_a(acc + bias)*free, one coalesced u64 store
__device__ __forceinline__ void epilogue_mt(
    f32x4 A, f32x4 B, float4 bb0, float4 bb1,
    const float* __restrict__ wallrow, unsigned char* __restrict__ Hn, int px){
  float fre = 1.0f - wallrow[px];
  float tA0 = tanh_a(A[0] + bb0.x)*fre;
  float tB0 = tanh_a(B[0] + bb1.x)*fre;
  float tA1 = tanh_a(A[1] + bb0.y)*fre;
  float tB1 = tanh_a(B[1] + bb1.y)*fre;
  float tA2 = tanh_a(A[2] + bb0.z)*fre;
  float tB2 = tanh_a(B[2] + bb1.z)*fre;
  float tA3 = tanh_a(A[3] + bb0.w)*fre;
  float tB3 = tanh_a(B[3] + bb1.w)*fre;
  int w0 = __builtin_amdgcn_cvt_pk_fp8_f32(tA0, tB0, 0, false);
  w0 = __builtin_amdgcn_cvt_pk_fp8_f32(tA1, tB1, w0, true);
  int w1 = __builtin_amdgcn_cvt_pk_fp8_f32(tA2, tB2, 0, false);
  w1 = __builtin_amdgcn_cvt_pk_fp8_f32(tA3, tB3, w1, true);
  *(uint2*)(Hn + (size_t)(px+1)*8) = (uint2){(unsigned)w0, (unsigned)w1};
}

// ST[64][32]: per-slot stat partials (atomics spread over 64 cache lines).
// PRM[0..2] = cos_a, sin_a, decay.
__global__ void k_prep(const float* angle, const float* decay_logit,
                       float* ST, float* PRM){
  int t = threadIdx.x;
  for (int i = t; i < 64*32; i += 256) ST[i] = 0.0f;
  if (t == 0){
    float ang = tanhf(angle[0])*0.02f;
    PRM[0] = cosf(ang);
    PRM[1] = sinf(ang);
    PRM[2] = 0.95f + 0.05f/(1.0f+expf(-decay_logit[0]));
  }
}

// WB8: fp8 weight fragments (first MFMA operand; row = lane&15 = oc_low,
// k = g*8+j -> HH record byte ch = chmap(k)).
// slots 0-8: tile0 taps 0-8; 9-17: tile1; 18: gate row.
// Center tap (s=4): +0.8 on oc==ch diagonal (folds 0.8*hh_old).
// WB16: bf16 tail fragments; k<16 -> tapA ch k; k>=16 -> tapB.
// slots 0-4: tile0 pair-steps; 5-9: tile1; 10: gate row (center-tap tail).
__global__ void k_wprep(const float* __restrict__ w_up, const float* __restrict__ w_gate,
                        u64* __restrict__ WB8, short8* __restrict__ WB16){
  int t = threadIdx.x;
  int lane = t & 63;
  int r_ = lane & 15, g = lane >> 4;
  for (int slot = t>>6; slot < 19; slot += 4){
    u64 v = 0;
    #pragma unroll
    for (int j=0;j<8;j++){
      float w = 0.f;
      int ch = chmap(g*8+j);
      if (slot < 18){
        int tile = slot/9, s = slot%9;
        int oc = tile*16 + r_;
        int dy=s/3, dx=s%3;
        w = w_up[((oc*42+ch)*3+dy)*3+dx];
        if (s==4 && oc==ch) w += 0.8f;
      } else {
        if (r_==0) w = w_gate[ch];
      }
      v |= ((u64)f2fp8(w)) << (8*j);
    }
    WB8[slot*64+lane] = v;
  }
  for (int slot = t>>6; slot < 11; slot += 4){
    short8 v;
    #pragma unroll
    for (int j=0;j<8;j++){
      float w = 0.f;
      int tt = (g&1)*8 + j;      // tail channel within tap
      int tapsel = g>>1;         // 0 = tapA, 1 = tapB
      if (slot < 10){
        int tile = slot/5, s2 = slot%5;
        int tap = 2*s2 + tapsel;
        int oc = tile*16 + r_;
        if (tap <= 8 && tt < 10){
          int src = (tt<4) ? (38+tt) : (32+(tt-4));
          int dy=tap/3, dx=tap%3;
          w = w_up[((oc*42+src)*3+dy)*3+dx];
        }
      } else {
        if (r_==0 && tapsel==0 && tt<10){
          int src = (tt<4) ? (38+tt) : (32+(tt-4));
          w = w_gate[src];
        }
      }
      v[j] = (short)f2bfu(w);
    }
    WB16[slot*64+lane] = v;
  }
}

__global__ void k_border(unsigned char* HH0, unsigned char* HH1,
                         unsigned char* TAIL0, unsigned char* TAIL1){
  int i = blockIdx.x*256 + threadIdx.x;
  if (i >= NB*PP) return;
  int b = i / PP, pp_ = i % PP;
  int row = pp_ / PW, col = pp_ % PW;
  if (row != 0 && row != 257 && col != 0 && col != 257) return;
  size_t rb = (size_t)(b*PW + row);
  #pragma unroll
  for (int g=0; g<4; g++){
    size_t a = (rb*4+g)*RHH + (size_t)col*8;
    *(uint2*)(HH0+a) = (uint2){0,0};
    *(uint2*)(HH1+a) = (uint2){0,0};
  }
  #pragma unroll
  for (int h=0; h<2; h++){
    size_t a = (rb*2+h)*RTT + (size_t)col*16;
    *(uint4*)(TAIL0+a) = (uint4){0,0,0,0};
    *(uint4*)(TAIL1+a) = (uint4){0,0,0,0};
  }
}

__global__ void k_init(const float* __restrict__ x, const float* __restrict__ w_in,
                       const float* __restrict__ b_in,
                       float* __restrict__ WALL,
                       unsigned char* __restrict__ HH0, unsigned char* __restrict__ TAIL0,
                       unsigned char* __restrict__ TAIL1, float* ST){
  int tid = threadIdx.x;
  int p = blockIdx.x*256 + tid;
  int b = p >> 16, rem = p & 65535;
  int y = rem >> 8, xc = rem & 255;
  const float* xb = x + (size_t)b*6*HW2D;
  float wall = xb[rem];
  float fre = 1.0f - wall;
  float s_r = xb[HW2D + rem]*fre;
  float s_i = xb[2*HW2D + rem]*fre;
  WALL[p] = wall;
  float src10[10];
  src10[0]=wall;
  #pragma unroll
  for (int c=1;c<6;c++) src10[c]=xb[c*HW2D+rem];
  src10[6]=s_r; src10[7]=s_i; src10[8]=s_r; src10[9]=s_i;
  float hv[32];
  #pragma unroll
  for (int c=0;c<32;c++){
    float a = b_in[c];
    #pragma unroll
    for (int k=0;k<10;k++) a += w_in[c*10+k]*src10[k];
    hv[c] = tanh_a(a)*fre;
  }
  // record byte 4w+t: ch {2w, 16+2w, 2w+1, 17+2w}; plane g = words 2g,2g+1
  unsigned int words[8];
  #pragma unroll
  for (int w=0;w<8;w++){
    int lo = __builtin_amdgcn_cvt_pk_fp8_f32(hv[2*w], hv[16+2*w], 0, false);
    words[w] = (unsigned int)__builtin_amdgcn_cvt_pk_fp8_f32(hv[2*w+1], hv[17+2*w], lo, true);
  }
  size_t rb = (size_t)(b*PW + y + 1);
  #pragma unroll
  for (int g=0; g<4; g++){
    *(uint2*)(HH0 + (rb*4+g)*RHH + (size_t)(xc+1)*8) = (uint2){words[2*g], words[2*g+1]};
  }
  unsigned short tv[16];
  tv[0]=f2bfu(s_r); tv[1]=f2bfu(s_i); tv[2]=f2bfu(s_r); tv[3]=f2bfu(s_i);
  #pragma unroll
  for (int c=0;c<6;c++) tv[4+c] = f2bfu(src10[c]);
  #pragma unroll
  for (int c=10;c<16;c++) tv[c] = 0;
  #pragma unroll
  for (int h=0; h<2; h++){
    short8 v;
    #pragma unroll
    for (int j=0;j<8;j++) v[j] = (short)tv[h*8+j];
    *(short8*)(TAIL0 + (rb*2+h)*RTT + (size_t)(xc+1)*16) = v;
    *(short8*)(TAIL1 + (rb*2+h)*RTT + (size_t)(xc+1)*16) = v;
  }
  float v = __builtin_amdgcn_sqrtf(s_r*s_r + s_i*s_i);
  #pragma unroll
  for (int off=32; off>0; off>>=1) v += __shfl_down(v, off);
  if ((tid&63)==0) atomicAdd(&ST[(blockIdx.x & 63)*32 + 16], v);
}

// Fused step, barrier-free, TWO-PASS conv (2 output sub-tiles per pass) to
// keep VGPR <= 64 -> 8 waves/SIMD for latency hiding.
__global__ __launch_bounds__(256, 8) void k_step(
    const unsigned char* __restrict__ HHo, unsigned char* __restrict__ HHn,
    const unsigned char* __restrict__ TAILo, unsigned char* __restrict__ TAILn,
    const float* __restrict__ WALL,
    const u64* __restrict__ WB8, const short8* __restrict__ WB16,
    const float* __restrict__ b_up, const float* __restrict__ x,
    const float* __restrict__ b_gate, const float* __restrict__ PRM,
    float* ST, int step){
  int bid = blockIdx.x;
  int b = bid & 7, y = bid >> 3;
  int tid = threadIdx.x;
  int wv = tid >> 6, lane = tid & 63;
  int r_ = lane & 15, g = lane >> 4;
  int px0 = wv*64 + r_;

  // ---- phase-B loads from TAILo (zero-padded -> branch-free stencil) ----
  const unsigned char* Tc = TAILo + (size_t)(b*PW + y + 1)*ROWB + (size_t)(tid+1)*16;
  unsigned int sw  = *(const unsigned int*)(Tc);            // s_r,s_i (bf16 pair)
  unsigned int fu  = *(const unsigned int*)(Tc - ROWB + 4); // f_r,f_i neighbors
  unsigned int fd  = *(const unsigned int*)(Tc + ROWB + 4);
  unsigned int fl  = *(const unsigned int*)(Tc - 16 + 4);
  unsigned int fr2 = *(const unsigned int*)(Tc + 16 + 4);
  float dlr = 0.f, dli = 0.f;
  if (step==8){
    const float* xb = x + (size_t)b*6*HW2D;
    int rem = (y<<8)+tid;
    dlr = xb[3*HW2D+rem]; dli = xb[4*HW2D+rem];
  }
  float wallB = WALL[b*HW2D + (y<<8) + tid];
  float ca = PRM[0], sa = PRM[1], dec = PRM[2];

  // ---- per-thread base pointers (conv loads = base + const imm) ----
  const unsigned char* Hrow = HHo + (size_t)(b*PW + y)*ROWB + (size_t)g*RHH + (size_t)px0*8;
  const unsigned char* Trow = TAILo + (size_t)(b*PW + y)*ROWB + (size_t)(g&1)*RTT + (size_t)px0*16;
  const unsigned char* Tzero = TAILo + (size_t)(b*PW)*ROWB + (size_t)(g&1)*RTT + (size_t)px0*16;
  int gb = g >> 1;
  const unsigned char* tb0 = Trow + (size_t)((0+gb)/3)*ROWB + (size_t)((0+gb)%3)*16;
  const unsigned char* tb1 = Trow + (size_t)((2+gb)/3)*ROWB + (size_t)((2+gb)%3)*16;
  const unsigned char* tb2 = Trow + (size_t)((4+gb)/3)*ROWB + (size_t)((4+gb)%3)*16;
  const unsigned char* tb3 = Trow + (size_t)((6+gb)/3)*ROWB + (size_t)((6+gb)%3)*16;
  const unsigned char* tb4 = gb ? Tzero : (Trow + 2*ROWB + 2*16);  // tap 8 or zero tap 9
  const u64* wb8l = WB8 + lane;
  const short8* wb16l = WB16 + lane;

  const float* wallrow = WALL + (size_t)b*HW2D + (y<<8);
  const float4* bup4 = (const float4*)b_up;
  float4 bb0 = bup4[g];
  float4 bb1 = bup4[4+g];
  unsigned char* Hn = HHn + ((size_t)(b*PW + y + 1)*4 + g)*RHH;

  float gpre = 0.0f;
  #pragma unroll
  for (int half=0; half<2; half++){
    const int mtA = half*2, mtB = half*2+1;
    f32x4 a00 = (f32x4){0.f,0.f,0.f,0.f};
    f32x4 a01 = (f32x4){0.f,0.f,0.f,0.f};
    f32x4 a10 = (f32x4){0.f,0.f,0.f,0.f};
    f32x4 a11 = (f32x4){0.f,0.f,0.f,0.f};
    f32x4 ag0 = (f32x4){0.f,0.f,0.f,0.f};
    f32x4 ag1 = (f32x4){0.f,0.f,0.f,0.f};

    __builtin_amdgcn_s_setprio(1);
    // seg1: 9 taps x 32 hh channels, fp8
    #pragma unroll
    for (int s=0;s<9;s++){
      u64 b0 = wb8l[s*64], b1 = wb8l[(9+s)*64];
      const int aoff = (s/3)*ROWB + (s%3)*8;
      u64 hA = *(const u64*)(Hrow + aoff + mtA*128);
      u64 hB = *(const u64*)(Hrow + aoff + mtB*128);
      a00 = __builtin_amdgcn_mfma_f32_16x16x32_fp8_fp8((long)b0, (long)hA, a00, 0,0,0);
      a01 = __builtin_amdgcn_mfma_f32_16x16x32_fp8_fp8((long)b1, (long)hA, a01, 0,0,0);
      a10 = __builtin_amdgcn_mfma_f32_16x16x32_fp8_fp8((long)b0, (long)hB, a10, 0,0,0);
      a11 = __builtin_amdgcn_mfma_f32_16x16x32_fp8_fp8((long)b1, (long)hB, a11, 0,0,0);
      if (s==4){
        u64 bg = wb8l[18*64];
        ag0 = __builtin_amdgcn_mfma_f32_16x16x32_fp8_fp8((long)bg, (long)hA, ag0, 0,0,0);
        ag1 = __builtin_amdgcn_mfma_f32_16x16x32_fp8_fp8((long)bg, (long)hB, ag1, 0,0,0);
      }
    }
    // seg2: 5 pair-steps x 16 tail channels, bf16
    #pragma unroll
    for (int s2=0;s2<5;s2++){
      short8 b0 = wb16l[s2*64], b1 = wb16l[(5+s2)*64];
      const unsigned char* tb = (s2==0)?tb0:(s2==1)?tb1:(s2==2)?tb2:(s2==3)?tb3:tb4;
      short8 tA = *(const short8*)(tb + mtA*256);
      short8 tB = *(const short8*)(tb + mtB*256);
      a00 = __builtin_amdgcn_mfma_f32_16x16x32_bf16(b0, tA, a00, 0,0,0);
      a01 = __builtin_amdgcn_mfma_f32_16x16x32_bf16(b1, tA, a01, 0,0,0);
      a10 = __builtin_amdgcn_mfma_f32_16x16x32_bf16(b0, tB, a10, 0,0,0);
      a11 = __builtin_amdgcn_mfma_f32_16x16x32_bf16(b1, tB, a11, 0,0,0);
      if (s2==2){
        short8 bgt = wb16l[10*64];
        ag0 = __builtin_amdgcn_mfma_f32_16x16x32_bf16(bgt, tA, ag0, 0,0,0);
        ag1 = __builtin_amdgcn_mfma_f32_16x16x32_bf16(bgt, tB, ag1, 0,0,0);
      }
    }
    __builtin_amdgcn_s_setprio(0);

    // gate extract (intra-wave): D row 0 = lanes 0-15 reg 0; col = pixel r_.
    // thread's own pixel group mt = g; take when mt in this half.
    float gA = __shfl(ag0[0], r_);
    float gB = __shfl(ag1[0], r_);
    if ((g>>1) == half) gpre = (g&1) ? gB : gA;

    // epilogue for this half's two sub-tiles (frees accumulators)
    epilogue_mt(a00, a01, bb0, bb1, wallrow, Hn, px0 + mtA*16);
    epilogue_mt(a10, a11, bb0, bb1, wallrow, Hn, px0 + mtB*16);
  }

  // ---- phase B (no barrier; all inputs are wave-local) ----
  float s_r = blo(sw), s_i = bhi(sw);
  float incr = blo(fu) + blo(fd) + blo(fl) + blo(fr2) + dlr;
  float inci = bhi(fu) + bhi(fd) + bhi(fl) + bhi(fr2) + dli;
  float fre = 1.0f - wallB;
  float a = gpre + b_gate[0];
  float gg = 0.998f + 0.002f*fast_sigmoid(a);
  incr *= gg; inci *= gg;
  float rr = incr*ca - inci*sa;
  float ri = incr*sa + inci*ca;
  incr = rr*fre; inci = ri*fre;
  float m1 = fmaf(incr,incr, fmaf(inci,inci, 1e-8f));
  float sc2 = fminf(2.0f*__builtin_amdgcn_rsqf(m1), 1.0f);
  incr *= sc2; inci *= sc2;
  float pw = (fabsf(incr)+fabsf(inci))*wallB;
  float nr = dec*s_r + incr, ni = dec*s_i + inci;
  float m2 = fmaf(nr,nr, fmaf(ni,ni, 1e-8f));
  sc2 = fminf(2.0f*__builtin_amdgcn_rsqf(m2), 1.0f);
  nr = nr*sc2*fre; ni = ni*sc2*fre;
  // TAIL write: row y+1, col tid+1, half 0, first 8 B = {s_r,s_i,f_r,f_i}
  ushort4 pk;
  pk.x = f2bfu(nr); pk.y = f2bfu(ni); pk.z = f2bfu(incr); pk.w = f2bfu(inci);
  *(ushort4*)(TAILn + (size_t)(b*PW + y + 1)*ROWB + (size_t)(tid+1)*16) = pk;
  float d2 = (nr-s_r)*(nr-s_r)+(ni-s_i)*(ni-s_i);
  float nrm = __builtin_amdgcn_sqrtf(nr*nr+ni*ni);
  #pragma unroll
  for (int off=32; off>0; off>>=1){
    d2  += __shfl_down(d2, off);
    nrm += __shfl_down(nrm, off);
    pw  += __shfl_down(pw, off);
  }
  if (step==16){
    // fused k_tail: sat/leak on final state (in-register, pre-rounding)
    float sat = (fabsf(nr)>4.0f ? 1.0f:0.0f) + (fabsf(ni)>4.0f ? 1.0f:0.0f);
    float nn = __builtin_amdgcn_sqrtf(nr*nr+ni*ni);
    float leak = (nn>0.5f && wallB>0.5f) ? 1.0f : 0.0f;
    #pragma unroll
    for (int off=32; off>0; off>>=1){
      sat  += __shfl_down(sat, off);
      leak += __shfl_down(leak, off);
    }
    if (lane==0){
      float* st = ST + ((bid*4+wv) & 63)*32;
      atomicAdd(&st[18], sat);
      atomicAdd(&st[19], leak);
    }
  }
  if (lane==0){
    float* st = ST + ((bid*4+wv) & 63)*32;
    atomicAdd(&st[step-1], d2);
    atomicAdd(&st[16],     nrm);
    atomicAdd(&st[17],     pw);
  }
}

__global__ void k_final(const unsigned char* __restrict__ TAIL, const int* __restrict__ target,
                        const float* __restrict__ ST, float* __restrict__ out){
  int t = threadIdx.x;   // 64 threads = one wave
  if (t < 8){
    int ty = target[2*t], tx = target[2*t+1];
    unsigned int sw = *(const unsigned int*)(TAIL + (size_t)(t*PW+ty+1)*ROWB + (size_t)(tx+1)*16);
    float vr = blo(sw), vi = bhi(sw);
    float mag = sqrtf(vr*vr+vi*vi+1e-8f);
    out[t*9] = (0.35f - mag)*12.0f;
    #pragma unroll
    for (int k=0;k<8;k++){
      float th = 6.283185307179586f * (float)k / 8.0f;
      out[t*9+1+k] = (vr*cosf(th)+vi*sinf(th) - 0.35f)*12.0f;
    }
  }
  // reduce ST[64][32] across slots (all 64 lanes participate)
  float tot[20];
  #pragma unroll
  for (int i=0;i<20;i++){
    float v = ST[t*32 + i];
    #pragma unroll
    for (int off=32; off>0; off>>=1) v += __shfl_down(v, off);
    tot[i] = v;   // valid on lane 0
  }
  if (t == 0){
    float d = 0.0f;
    #pragma unroll
    for (int s=0;s<16;s++) d += sqrtf(tot[s]/1048576.0f);
    out[72] = d/16.0f;
    out[73] = tot[16]/8912896.0f;
    out[74] = tot[18]/1048576.0f;
    out[75] = tot[17]/(524288.0f*16.0f);
    out[76] = tot[19]/524288.0f;
  }
}

extern "C" void kernel_launch(void* const* d_in, const int* in_sizes, int n_in,
                              void* d_out, int out_size, void* d_ws, size_t ws_size,
                              hipStream_t stream) {
  const float* x       = (const float*)d_in[0];
  const int*   target  = (const int*)  d_in[1];
  const float* w_in    = (const float*)d_in[2];
  const float* b_in    = (const float*)d_in[3];
  const float* w_up    = (const float*)d_in[4];
  const float* b_up    = (const float*)d_in[5];
  const float* w_gate  = (const float*)d_in[6];
  const float* b_gate  = (const float*)d_in[7];
  const float* angle   = (const float*)d_in[8];
  const float* decay_l = (const float*)d_in[9];
  float* out = (float*)d_out;

  char* ws = (char*)d_ws;
  size_t off = 0;
  unsigned char* HH0 = (unsigned char*)(ws+off); off += (size_t)NB*PP*32;
  unsigned char* HH1 = (unsigned char*)(ws+off); off += (size_t)NB*PP*32;
  unsigned char* TAIL0=(unsigned char*)(ws+off); off += (size_t)NB*PP*32;
  unsigned char* TAIL1=(unsigned char*)(ws+off); off += (size_t)NB*PP*32;
  float* WALL = (float*)(ws+off); off += (size_t)NPIX*4;
  u64* WB8 = (u64*)(ws+off); off += (size_t)19*64*8;
  short8* WB16 = (short8*)(ws+off); off += (size_t)11*64*16;
  float* ST = (float*)(ws+off); off += (size_t)64*32*4;
  float* PRM = (float*)(ws+off); off += 16*4;

  k_prep<<<1,256,0,stream>>>(angle, decay_l, ST, PRM);
  k_wprep<<<1,256,0,stream>>>(w_up, w_gate, WB8, WB16);
  k_border<<<(NB*PP+255)/256,256,0,stream>>>(HH0, HH1, TAIL0, TAIL1);
  k_init<<<NPIX/256,256,0,stream>>>(x, w_in, b_in, WALL, HH0, TAIL0, TAIL1, ST);

  unsigned char *hho=HH0, *hhn=HH1, *tlo=TAIL0, *tln=TAIL1;
  for (int t=1;t<=NSTEPS;t++){
    k_step<<<2048,256,0,stream>>>(hho, hhn, tlo, tln, WALL,
                                  WB8, WB16, b_up, x, b_gate, PRM, ST, t);
    unsigned char* tc=hho; hho=hhn; hhn=tc;
    tc=tlo; tlo=tln; tln=tc;
  }
  k_final<<<1,64,0,stream>>>(tlo, target, ST, out);
}

// Round 14
// 535.028 us; speedup vs baseline: 1.7973x; 1.7973x over previous
//
#include <hip/hip_runtime.h>
#include <hip/hip_bf16.h>

#define HW2D 65536
#define NPIX 524288   // 8 * 65536
#define NB 8
#define PW 258
#define PP 66564      // 258*258
#define NSTEPS 16
#define RHH 2064      // 258*8  : HH plane stride (bytes)
#define RTT 4128      // 258*16 : TAIL half stride (bytes)
#define ROWB 8256     // 258*32 : full row stride (bytes), = 4*RHH = 2*RTT

typedef __hip_bfloat16 bf16;
typedef unsigned long long u64;
typedef __attribute__((ext_vector_type(8))) short short8;
typedef __attribute__((ext_vector_type(4))) float f32x4;

__device__ __forceinline__ unsigned short f2bfu(float v){
  bf16 h = __float2bfloat16(v); return *(unsigned short*)&h;
}
__device__ __forceinline__ float blo(unsigned int w){ return __uint_as_float(w<<16); }
__device__ __forceinline__ float bhi(unsigned int w){ return __uint_as_float(w & 0xffff0000u); }
// cheap odd tanh approx (max abs err ~0.055); hh reaches the wave state only
// through the 0.002*sigmoid gate, so downstream error is negligible
__device__ __forceinline__ float tanh_a(float z){
  return z*__builtin_amdgcn_rsqf(fmaf(z, z, 1.0f));
}
__device__ __forceinline__ float fast_sigmoid(float z){
  return 1.0f/(1.0f + __expf(-z));
}
__device__ __forceinline__ unsigned char f2fp8(float v){
  return (unsigned char)(__builtin_amdgcn_cvt_pk_fp8_f32(v, 0.f, 0, false) & 0xFF);
}
// record byte m <-> channel ch(m) = (m>>1) + (m&1)*16 ; plane g = bytes 8g..8g+7
__device__ __forceinline__ int chmap(int m){ return (m>>1) + (m&1)*16; }

// ST[64][32]: per-slot stat partials (atomics spread over 64 cache lines).
// PRM[0..2] = cos_a, sin_a, decay.
__global__ void k_prep(const float* angle, const float* decay_logit,
                       float* ST, float* PRM){
  int t = threadIdx.x;
  for (int i = t; i < 64*32; i += 256) ST[i] = 0.0f;
  if (t == 0){
    float ang = tanhf(angle[0])*0.02f;
    PRM[0] = cosf(ang);
    PRM[1] = sinf(ang);
    PRM[2] = 0.95f + 0.05f/(1.0f+expf(-decay_logit[0]));
  }
}

// WB8: fp8 weight fragments (first MFMA operand; row = lane&15 = oc_low,
// k = g*8+j -> HH record byte ch = chmap(k)).
// slots 0-8: tile0 taps 0-8; 9-17: tile1; 18: gate row.
// Center tap (s=4): +0.8 on oc==ch diagonal (folds 0.8*hh_old).
// WB16: bf16 tail fragments; k<16 -> tapA ch k; k>=16 -> tapB.
// slots 0-4: tile0 pair-steps; 5-9: tile1; 10: gate row (center-tap tail).
__global__ void k_wprep(const float* __restrict__ w_up, const float* __restrict__ w_gate,
                        u64* __restrict__ WB8, short8* __restrict__ WB16){
  int t = threadIdx.x;
  int lane = t & 63;
  int r_ = lane & 15, g = lane >> 4;
  for (int slot = t>>6; slot < 19; slot += 4){
    u64 v = 0;
    #pragma unroll
    for (int j=0;j<8;j++){
      float w = 0.f;
      int ch = chmap(g*8+j);
      if (slot < 18){
        int tile = slot/9, s = slot%9;
        int oc = tile*16 + r_;
        int dy=s/3, dx=s%3;
        w = w_up[((oc*42+ch)*3+dy)*3+dx];
        if (s==4 && oc==ch) w += 0.8f;
      } else {
        if (r_==0) w = w_gate[ch];
      }
      v |= ((u64)f2fp8(w)) << (8*j);
    }
    WB8[slot*64+lane] = v;
  }
  for (int slot = t>>6; slot < 11; slot += 4){
    short8 v;
    #pragma unroll
    for (int j=0;j<8;j++){
      float w = 0.f;
      int tt = (g&1)*8 + j;      // tail channel within tap
      int tapsel = g>>1;         // 0 = tapA, 1 = tapB
      if (slot < 10){
        int tile = slot/5, s2 = slot%5;
        int tap = 2*s2 + tapsel;
        int oc = tile*16 + r_;
        if (tap <= 8 && tt < 10){
          int src = (tt<4) ? (38+tt) : (32+(tt-4));
          int dy=tap/3, dx=tap%3;
          w = w_up[((oc*42+src)*3+dy)*3+dx];
        }
      } else {
        if (r_==0 && tapsel==0 && tt<10){
          int src = (tt<4) ? (38+tt) : (32+(tt-4));
          w = w_gate[src];
        }
      }
      v[j] = (short)f2bfu(w);
    }
    WB16[slot*64+lane] = v;
  }
}

__global__ void k_border(unsigned char* HH0, unsigned char* HH1,
                         unsigned char* TAIL0, unsigned char* TAIL1){
  int i = blockIdx.x*256 + threadIdx.x;
  if (i >= NB*PP) return;
  int b = i / PP, pp_ = i % PP;
  int row = pp_ / PW, col = pp_ % PW;
  if (row != 0 && row != 257 && col != 0 && col != 257) return;
  size_t rb = (size_t)(b*PW + row);
  #pragma unroll
  for (int g=0; g<4; g++){
    size_t a = (rb*4+g)*RHH + (size_t)col*8;
    *(uint2*)(HH0+a) = (uint2){0,0};
    *(uint2*)(HH1+a) = (uint2){0,0};
  }
  #pragma unroll
  for (int h=0; h<2; h++){
    size_t a = (rb*2+h)*RTT + (size_t)col*16;
    *(uint4*)(TAIL0+a) = (uint4){0,0,0,0};
    *(uint4*)(TAIL1+a) = (uint4){0,0,0,0};
  }
}

__global__ void k_init(const float* __restrict__ x, const float* __restrict__ w_in,
                       const float* __restrict__ b_in,
                       float* __restrict__ WALL,
                       unsigned char* __restrict__ HH0, unsigned char* __restrict__ TAIL0,
                       unsigned char* __restrict__ TAIL1, float* ST){
  int tid = threadIdx.x;
  int p = blockIdx.x*256 + tid;
  int b = p >> 16, rem = p & 65535;
  int y = rem >> 8, xc = rem & 255;
  const float* xb = x + (size_t)b*6*HW2D;
  float wall = xb[rem];
  float fre = 1.0f - wall;
  float s_r = xb[HW2D + rem]*fre;
  float s_i = xb[2*HW2D + rem]*fre;
  WALL[p] = wall;
  float src10[10];
  src10[0]=wall;
  #pragma unroll
  for (int c=1;c<6;c++) src10[c]=xb[c*HW2D+rem];
  src10[6]=s_r; src10[7]=s_i; src10[8]=s_r; src10[9]=s_i;
  float hv[32];
  #pragma unroll
  for (int c=0;c<32;c++){
    float a = b_in[c];
    #pragma unroll
    for (int k=0;k<10;k++) a += w_in[c*10+k]*src10[k];
    hv[c] = tanh_a(a)*fre;
  }
  // record byte 4w+t: ch {2w, 16+2w, 2w+1, 17+2w}; plane g = words 2g,2g+1
  unsigned int words[8];
  #pragma unroll
  for (int w=0;w<8;w++){
    int lo = __builtin_amdgcn_cvt_pk_fp8_f32(hv[2*w], hv[16+2*w], 0, false);
    words[w] = (unsigned int)__builtin_amdgcn_cvt_pk_fp8_f32(hv[2*w+1], hv[17+2*w], lo, true);
  }
  size_t rb = (size_t)(b*PW + y + 1);
  #pragma unroll
  for (int g=0; g<4; g++){
    *(uint2*)(HH0 + (rb*4+g)*RHH + (size_t)(xc+1)*8) = (uint2){words[2*g], words[2*g+1]};
  }
  unsigned short tv[16];
  tv[0]=f2bfu(s_r); tv[1]=f2bfu(s_i); tv[2]=f2bfu(s_r); tv[3]=f2bfu(s_i);
  #pragma unroll
  for (int c=0;c<6;c++) tv[4+c] = f2bfu(src10[c]);
  #pragma unroll
  for (int c=10;c<16;c++) tv[c] = 0;
  #pragma unroll
  for (int h=0; h<2; h++){
    short8 v;
    #pragma unroll
    for (int j=0;j<8;j++) v[j] = (short)tv[h*8+j];
    *(short8*)(TAIL0 + (rb*2+h)*RTT + (size_t)(xc+1)*16) = v;
    *(short8*)(TAIL1 + (rb*2+h)*RTT + (size_t)(xc+1)*16) = v;
  }
  float v = __builtin_amdgcn_sqrtf(s_r*s_r + s_i*s_i);
  #pragma unroll
  for (int off=32; off>0; off>>=1) v += __shfl_down(v, off);
  if ((tid&63)==0) atomicAdd(&ST[(blockIdx.x & 63)*32 + 16], v);
}

// Fused step, barrier-free, TWO ROWS per block (grid = 1024): full residency
// (16 waves/CU) + L1/L2 reuse of the 2 shared tap rows between the two convs.
__global__ __launch_bounds__(256) void k_step(
    const unsigned char* __restrict__ HHo, unsigned char* __restrict__ HHn,
    const unsigned char* __restrict__ TAILo, unsigned char* __restrict__ TAILn,
    const float* __restrict__ WALL,
    const u64* __restrict__ WB8, const short8* __restrict__ WB16,
    const float* __restrict__ b_up, const float* __restrict__ x,
    const float* __restrict__ b_gate, const float* __restrict__ PRM,
    float* ST, int step){
  int bid = blockIdx.x;
  int b = bid & 7, y0 = (bid >> 3) << 1;
  int tid = threadIdx.x;
  int wv = tid >> 6, lane = tid & 63;
  int r_ = lane & 15, g = lane >> 4;
  int px0 = wv*64 + r_;

  // ---- hoisted phase-B loads for BOTH rows (zero-padded, branch-free) ----
  const unsigned char* Tc0 = TAILo + (size_t)(b*PW + y0 + 1)*ROWB + (size_t)(tid+1)*16;
  const unsigned char* Tc1 = Tc0 + ROWB;
  unsigned int sw0 = *(const unsigned int*)(Tc0);
  unsigned int sw1 = *(const unsigned int*)(Tc1);
  unsigned int fu0 = *(const unsigned int*)(Tc0 - ROWB + 4);
  unsigned int fc0 = *(const unsigned int*)(Tc0 + 4);        // row A f (= row B's up)
  unsigned int fc1 = *(const unsigned int*)(Tc1 + 4);        // row B f (= row A's down)
  unsigned int fd1 = *(const unsigned int*)(Tc1 + ROWB + 4);
  unsigned int fl0 = *(const unsigned int*)(Tc0 - 16 + 4);
  unsigned int fr0 = *(const unsigned int*)(Tc0 + 16 + 4);
  unsigned int fl1 = *(const unsigned int*)(Tc1 - 16 + 4);
  unsigned int fr1 = *(const unsigned int*)(Tc1 + 16 + 4);
  float wall0 = WALL[b*HW2D + (y0<<8) + tid];
  float wall1 = WALL[b*HW2D + ((y0+1)<<8) + tid];
  float dlr0=0.f, dli0=0.f, dlr1=0.f, dli1=0.f;
  if (step==8){
    const float* xb = x + (size_t)b*6*HW2D;
    int rem0 = (y0<<8)+tid;
    dlr0 = xb[3*HW2D+rem0]; dli0 = xb[4*HW2D+rem0];
    dlr1 = xb[3*HW2D+rem0+256]; dli1 = xb[4*HW2D+rem0+256];
  }
  float ca = PRM[0], sa = PRM[1], dec = PRM[2];

  const u64* wb8l = WB8 + lane;
  const short8* wb16l = WB16 + lane;
  const float4* bup4 = (const float4*)b_up;
  float4 bb0 = bup4[g];
  float4 bb1 = bup4[4+g];
  const unsigned char* Tzero = TAILo + (size_t)(b*PW)*ROWB + (size_t)(g&1)*RTT + (size_t)px0*16;
  int gb = g >> 1;

  float d2s=0.f, nrms=0.f, pws=0.f, sats=0.f, leaks=0.f;

  #pragma unroll
  for (int ry=0; ry<2; ry++){
    int y = y0 + ry;
    // ---- per-row base pointers (conv loads = base + const imm) ----
    const unsigned char* Hrow = HHo + (size_t)(b*PW + y)*ROWB + (size_t)g*RHH + (size_t)px0*8;
    const unsigned char* Trow = TAILo + (size_t)(b*PW + y)*ROWB + (size_t)(g&1)*RTT + (size_t)px0*16;
    const unsigned char* tb0 = Trow + (size_t)((0+gb)/3)*ROWB + (size_t)((0+gb)%3)*16;
    const unsigned char* tb1 = Trow + (size_t)((2+gb)/3)*ROWB + (size_t)((2+gb)%3)*16;
    const unsigned char* tb2 = Trow + (size_t)((4+gb)/3)*ROWB + (size_t)((4+gb)%3)*16;
    const unsigned char* tb3 = Trow + (size_t)((6+gb)/3)*ROWB + (size_t)((6+gb)%3)*16;
    const unsigned char* tb4 = gb ? Tzero : (Trow + 2*ROWB + 2*16);

    f32x4 acc[4][2], accg[4];
    #pragma unroll
    for (int mt=0;mt<4;mt++){
      acc[mt][0] = (f32x4){0.f,0.f,0.f,0.f};
      acc[mt][1] = (f32x4){0.f,0.f,0.f,0.f};
      accg[mt]   = (f32x4){0.f,0.f,0.f,0.f};
    }

    __builtin_amdgcn_s_setprio(1);
    // seg1: 9 taps x 32 hh channels, fp8
    #pragma unroll
    for (int s=0;s<9;s++){
      u64 b0 = wb8l[s*64], b1 = wb8l[(9+s)*64];
      u64 aH[4];
      #pragma unroll
      for (int mt=0;mt<4;mt++)
        aH[mt] = *(const u64*)(Hrow + (size_t)((s/3)*ROWB) + ((s%3)*8 + mt*128));
      #pragma unroll
      for (int mt=0;mt<4;mt++){
        acc[mt][0] = __builtin_amdgcn_mfma_f32_16x16x32_fp8_fp8((long)b0, (long)aH[mt], acc[mt][0], 0,0,0);
        acc[mt][1] = __builtin_amdgcn_mfma_f32_16x16x32_fp8_fp8((long)b1, (long)aH[mt], acc[mt][1], 0,0,0);
      }
      if (s==4){
        u64 bg = wb8l[18*64];
        #pragma unroll
        for (int mt=0;mt<4;mt++)
          accg[mt] = __builtin_amdgcn_mfma_f32_16x16x32_fp8_fp8((long)bg, (long)aH[mt], accg[mt], 0,0,0);
      }
    }
    // seg2: 5 pair-steps x 16 tail channels, bf16
    #pragma unroll
    for (int s2=0;s2<5;s2++){
      short8 b0 = wb16l[s2*64], b1 = wb16l[(5+s2)*64];
      const unsigned char* tb = (s2==0)?tb0:(s2==1)?tb1:(s2==2)?tb2:(s2==3)?tb3:tb4;
      short8 aT[4];
      #pragma unroll
      for (int mt=0;mt<4;mt++)
        aT[mt] = *(const short8*)(tb + mt*256);
      #pragma unroll
      for (int mt=0;mt<4;mt++){
        acc[mt][0] = __builtin_amdgcn_mfma_f32_16x16x32_bf16(b0, aT[mt], acc[mt][0], 0,0,0);
        acc[mt][1] = __builtin_amdgcn_mfma_f32_16x16x32_bf16(b1, aT[mt], acc[mt][1], 0,0,0);
      }
      if (s2==2){
        short8 bgt = wb16l[10*64];
        #pragma unroll
        for (int mt=0;mt<4;mt++)
          accg[mt] = __builtin_amdgcn_mfma_f32_16x16x32_bf16(bgt, aT[mt], accg[mt], 0,0,0);
      }
    }
    __builtin_amdgcn_s_setprio(0);

    // gate redistribution, intra-wave: pull from lane r_; select by g
    float ga0 = __shfl(accg[0][0], r_);
    float ga1 = __shfl(accg[1][0], r_);
    float ga2 = __shfl(accg[2][0], r_);
    float ga3 = __shfl(accg[3][0], r_);
    float gpre = (g==0) ? ga0 : (g==1) ? ga1 : (g==2) ? ga2 : ga3;

    // ---- epilogue: hh_new = tanh_a(acc + bias)*free ----
    const float* wallrow = WALL + (size_t)b*HW2D + (y<<8);
    unsigned char* Hn = HHn + ((size_t)(b*PW + y + 1)*4 + g)*RHH;
    #pragma unroll
    for (int mt=0;mt<4;mt++){
      int px = px0 + mt*16;
      float fre = 1.0f - wallrow[px];
      float tA0 = tanh_a(acc[mt][0][0] + bb0.x)*fre;
      float tB0 = tanh_a(acc[mt][1][0] + bb1.x)*fre;
      float tA1 = tanh_a(acc[mt][0][1] + bb0.y)*fre;
      float tB1 = tanh_a(acc[mt][1][1] + bb1.y)*fre;
      float tA2 = tanh_a(acc[mt][0][2] + bb0.z)*fre;
      float tB2 = tanh_a(acc[mt][1][2] + bb1.z)*fre;
      float tA3 = tanh_a(acc[mt][0][3] + bb0.w)*fre;
      float tB3 = tanh_a(acc[mt][1][3] + bb1.w)*fre;
      int w0 = __builtin_amdgcn_cvt_pk_fp8_f32(tA0, tB0, 0, false);
      w0 = __builtin_amdgcn_cvt_pk_fp8_f32(tA1, tB1, w0, true);
      int w1 = __builtin_amdgcn_cvt_pk_fp8_f32(tA2, tB2, 0, false);
      w1 = __builtin_amdgcn_cvt_pk_fp8_f32(tA3, tB3, w1, true);
      *(uint2*)(Hn + (size_t)(px+1)*8) = (uint2){(unsigned)w0, (unsigned)w1};
    }

    // ---- phase B for this row (wave-local) ----
    unsigned int sw  = ry ? sw1 : sw0;
    unsigned int fu  = ry ? fc0 : fu0;
    unsigned int fd  = ry ? fd1 : fc1;
    unsigned int fl  = ry ? fl1 : fl0;
    unsigned int fr2 = ry ? fr1 : fr0;
    float wallB = ry ? wall1 : wall0;
    float dlr = ry ? dlr1 : dlr0, dli = ry ? dli1 : dli0;

    float s_r = blo(sw), s_i = bhi(sw);
    float incr = blo(fu) + blo(fd) + blo(fl) + blo(fr2) + dlr;
    float inci = bhi(fu) + bhi(fd) + bhi(fl) + bhi(fr2) + dli;
    float fre = 1.0f - wallB;
    float a = gpre + b_gate[0];
    float gg = 0.998f + 0.002f*fast_sigmoid(a);
    incr *= gg; inci *= gg;
    float rr = incr*ca - inci*sa;
    float ri = incr*sa + inci*ca;
    incr = rr*fre; inci = ri*fre;
    float m1 = fmaf(incr,incr, fmaf(inci,inci, 1e-8f));
    float sc2 = fminf(2.0f*__builtin_amdgcn_rsqf(m1), 1.0f);
    incr *= sc2; inci *= sc2;
    pws += (fabsf(incr)+fabsf(inci))*wallB;
    float nr = dec*s_r + incr, ni = dec*s_i + inci;
    float m2 = fmaf(nr,nr, fmaf(ni,ni, 1e-8f));
    sc2 = fminf(2.0f*__builtin_amdgcn_rsqf(m2), 1.0f);
    nr = nr*sc2*fre; ni = ni*sc2*fre;
    ushort4 pk;
    pk.x = f2bfu(nr); pk.y = f2bfu(ni); pk.z = f2bfu(incr); pk.w = f2bfu(inci);
    *(ushort4*)(TAILn + (size_t)(b*PW + y + 1)*ROWB + (size_t)(tid+1)*16) = pk;
    d2s  += (nr-s_r)*(nr-s_r)+(ni-s_i)*(ni-s_i);
    nrms += __builtin_amdgcn_sqrtf(nr*nr+ni*ni);
    if (step==16){
      sats  += (fabsf(nr)>4.0f ? 1.0f:0.0f) + (fabsf(ni)>4.0f ? 1.0f:0.0f);
      float nn = __builtin_amdgcn_sqrtf(nr*nr+ni*ni);
      leaks += (nn>0.5f && wallB>0.5f) ? 1.0f : 0.0f;
    }
  }

  // ---- single stat reduction for both rows ----
  #pragma unroll
  for (int off=32; off>0; off>>=1){
    d2s  += __shfl_down(d2s, off);
    nrms += __shfl_down(nrms, off);
    pws  += __shfl_down(pws, off);
  }
  if (step==16){
    #pragma unroll
    for (int off=32; off>0; off>>=1){
      sats  += __shfl_down(sats, off);
      leaks += __shfl_down(leaks, off);
    }
    if (lane==0){
      float* st = ST + ((bid*4+wv) & 63)*32;
      atomicAdd(&st[18], sats);
      atomicAdd(&st[19], leaks);
    }
  }
  if (lane==0){
    float* st = ST + ((bid*4+wv) & 63)*32;
    atomicAdd(&st[step-1], d2s);
    atomicAdd(&st[16],     nrms);
    atomicAdd(&st[17],     pws);
  }
}

__global__ void k_final(const unsigned char* __restrict__ TAIL, const int* __restrict__ target,
                        const float* __restrict__ ST, float* __restrict__ out){
  int t = threadIdx.x;   // 64 threads = one wave
  if (t < 8){
    int ty = target[2*t], tx = target[2*t+1];
    unsigned int sw = *(const unsigned int*)(TAIL + (size_t)(t*PW+ty+1)*ROWB + (size_t)(tx+1)*16);
    float vr = blo(sw), vi = bhi(sw);
    float mag = sqrtf(vr*vr+vi*vi+1e-8f);
    out[t*9] = (0.35f - mag)*12.0f;
    #pragma unroll
    for (int k=0;k<8;k++){
      float th = 6.283185307179586f * (float)k / 8.0f;
      out[t*9+1+k] = (vr*cosf(th)+vi*sinf(th) - 0.35f)*12.0f;
    }
  }
  // reduce ST[64][32] across slots (all 64 lanes participate)
  float tot[20];
  #pragma unroll
  for (int i=0;i<20;i++){
    float v = ST[t*32 + i];
    #pragma unroll
    for (int off=32; off>0; off>>=1) v += __shfl_down(v, off);
    tot[i] = v;   // valid on lane 0
  }
  if (t == 0){
    float d = 0.0f;
    #pragma unroll
    for (int s=0;s<16;s++) d += sqrtf(tot[s]/1048576.0f);
    out[72] = d/16.0f;
    out[73] = tot[16]/8912896.0f;
    out[74] = tot[18]/1048576.0f;
    out[75] = tot[17]/(524288.0f*16.0f);
    out[76] = tot[19]/524288.0f;
  }
}

extern "C" void kernel_launch(void* const* d_in, const int* in_sizes, int n_in,
                              void* d_out, int out_size, void* d_ws, size_t ws_size,
                              hipStream_t stream) {
  const float* x       = (const float*)d_in[0];
  const int*   target  = (const int*)  d_in[1];
  const float* w_in    = (const float*)d_in[2];
  const float* b_in    = (const float*)d_in[3];
  const float* w_up    = (const float*)d_in[4];
  const float* b_up    = (const float*)d_in[5];
  const float* w_gate  = (const float*)d_in[6];
  const float* b_gate  = (const float*)d_in[7];
  const float* angle   = (const float*)d_in[8];
  const float* decay_l = (const float*)d_in[9];
  float* out = (float*)d_out;

  char* ws = (char*)d_ws;
  size_t off = 0;
  unsigned char* HH0 = (unsigned char*)(ws+off); off += (size_t)NB*PP*32;
  unsigned char* HH1 = (unsigned char*)(ws+off); off += (size_t)NB*PP*32;
  unsigned char* TAIL0=(unsigned char*)(ws+off); off += (size_t)NB*PP*32;
  unsigned char* TAIL1=(unsigned char*)(ws+off); off += (size_t)NB*PP*32;
  float* WALL = (float*)(ws+off); off += (size_t)NPIX*4;
  u64* WB8 = (u64*)(ws+off); off += (size_t)19*64*8;
  short8* WB16 = (short8*)(ws+off); off += (size_t)11*64*16;
  float* ST = (float*)(ws+off); off += (size_t)64*32*4;
  float* PRM = (float*)(ws+off); off += 16*4;

  k_prep<<<1,256,0,stream>>>(angle, decay_l, ST, PRM);
  k_wprep<<<1,256,0,stream>>>(w_up, w_gate, WB8, WB16);
  k_border<<<(NB*PP+255)/256,256,0,stream>>>(HH0, HH1, TAIL0, TAIL1);
  k_init<<<NPIX/256,256,0,stream>>>(x, w_in, b_in, WALL, HH0, TAIL0, TAIL1, ST);

  unsigned char *hho=HH0, *hhn=HH1, *tlo=TAIL0, *tln=TAIL1;
  for (int t=1;t<=NSTEPS;t++){
    k_step<<<1024,256,0,stream>>>(hho, hhn, tlo, tln, WALL,
                                  WB8, WB16, b_up, x, b_gate, PRM, ST, t);
    unsigned char* tc=hho; hho=hhn; hhn=tc;
    tc=tlo; tlo=tln; tln=tc;
  }
  k_final<<<1,64,0,stream>>>(tlo, target, ST, out);
}

// Round 15
// 503.526 us; speedup vs baseline: 1.9097x; 1.0626x over previous
//
#include <hip/hip_runtime.h>
#include <hip/hip_bf16.h>

#define HW2D 65536
#define NPIX 524288   // 8 * 65536
#define NB 8
#define PW 258
#define PP 66564      // 258*258
#define NSTEPS 16
#define RHH 2064      // 258*8  : HH plane stride (bytes)
#define RTT 4128      // 258*16 : TAIL half stride (bytes)
#define ROWB 8256     // 258*32 : full row stride (bytes), = 4*RHH = 2*RTT

typedef __hip_bfloat16 bf16;
typedef unsigned long long u64;
typedef __attribute__((ext_vector_type(8))) short short8;
typedef __attribute__((ext_vector_type(4))) float f32x4;

__device__ __forceinline__ unsigned short f2bfu(float v){
  bf16 h = __float2bfloat16(v); return *(unsigned short*)&h;
}
__device__ __forceinline__ float blo(unsigned int w){ return __uint_as_float(w<<16); }
__device__ __forceinline__ float bhi(unsigned int w){ return __uint_as_float(w & 0xffff0000u); }
// cheap odd tanh approx (max abs err ~0.055); hh reaches the wave state only
// through the 0.002*sigmoid gate, so downstream error is negligible
__device__ __forceinline__ float tanh_a(float z){
  return z*__builtin_amdgcn_rsqf(fmaf(z, z, 1.0f));
}
__device__ __forceinline__ float fast_sigmoid(float z){
  return 1.0f/(1.0f + __expf(-z));
}
__device__ __forceinline__ unsigned char f2fp8(float v){
  return (unsigned char)(__builtin_amdgcn_cvt_pk_fp8_f32(v, 0.f, 0, false) & 0xFF);
}
// record byte m <-> channel ch(m) = (m>>1) + (m&1)*16 ; plane g = bytes 8g..8g+7
__device__ __forceinline__ int chmap(int m){ return (m>>1) + (m&1)*16; }

// Fused setup: ST zero + PRM scalars + weight fragment prep (one block).
// WB8: fp8 weight fragments (first MFMA operand; row = lane&15 = oc_low,
// k = g*8+j -> HH record byte ch = chmap(k)).
// slots 0-8: tile0 taps 0-8; 9-17: tile1; 18: gate row.
// Center tap (s=4): +0.8 on oc==ch diagonal (folds 0.8*hh_old).
// WB16: bf16 tail fragments; k<16 -> tapA ch k; k>=16 -> tapB.
// slots 0-4: tile0 pair-steps; 5-9: tile1; 10: gate row (center-tap tail).
__global__ void k_setup(const float* __restrict__ w_up, const float* __restrict__ w_gate,
                        const float* angle, const float* decay_logit,
                        u64* __restrict__ WB8, short8* __restrict__ WB16,
                        float* ST, float* PRM){
  int t = threadIdx.x;
  for (int i = t; i < 64*32; i += 256) ST[i] = 0.0f;
  if (t == 0){
    float ang = tanhf(angle[0])*0.02f;
    PRM[0] = cosf(ang);
    PRM[1] = sinf(ang);
    PRM[2] = 0.95f + 0.05f/(1.0f+expf(-decay_logit[0]));
  }
  int lane = t & 63;
  int r_ = lane & 15, g = lane >> 4;
  for (int slot = t>>6; slot < 19; slot += 4){
    u64 v = 0;
    #pragma unroll
    for (int j=0;j<8;j++){
      float w = 0.f;
      int ch = chmap(g*8+j);
      if (slot < 18){
        int tile = slot/9, s = slot%9;
        int oc = tile*16 + r_;
        int dy=s/3, dx=s%3;
        w = w_up[((oc*42+ch)*3+dy)*3+dx];
        if (s==4 && oc==ch) w += 0.8f;
      } else {
        if (r_==0) w = w_gate[ch];
      }
      v |= ((u64)f2fp8(w)) << (8*j);
    }
    WB8[slot*64+lane] = v;
  }
  for (int slot = t>>6; slot < 11; slot += 4){
    short8 v;
    #pragma unroll
    for (int j=0;j<8;j++){
      float w = 0.f;
      int tt = (g&1)*8 + j;      // tail channel within tap
      int tapsel = g>>1;         // 0 = tapA, 1 = tapB
      if (slot < 10){
        int tile = slot/5, s2 = slot%5;
        int tap = 2*s2 + tapsel;
        int oc = tile*16 + r_;
        if (tap <= 8 && tt < 10){
          int src = (tt<4) ? (38+tt) : (32+(tt-4));
          int dy=tap/3, dx=tap%3;
          w = w_up[((oc*42+src)*3+dy)*3+dx];
        }
      } else {
        if (r_==0 && tapsel==0 && tt<10){
          int src = (tt<4) ? (38+tt) : (32+(tt-4));
          w = w_gate[src];
        }
      }
      v[j] = (short)f2bfu(w);
    }
    WB16[slot*64+lane] = v;
  }
}

// Fused init + border: one thread per PADDED pixel. Border lanes zero the pad
// ring of both HH and both TAIL buffers; interior lanes compute the init
// state. No early returns (all lanes join the wave stat reduction).
__global__ void k_init(const float* __restrict__ x, const float* __restrict__ w_in,
                       const float* __restrict__ b_in,
                       float* __restrict__ WALL,
                       unsigned char* __restrict__ HH0, unsigned char* __restrict__ HH1,
                       unsigned char* __restrict__ TAIL0, unsigned char* __restrict__ TAIL1,
                       float* ST){
  int tid = threadIdx.x;
  int i = blockIdx.x*256 + tid;
  float v = 0.0f;
  if (i < NB*PP){
    int b = i / PP, pp_ = i % PP;
    int row = pp_ / PW, col = pp_ % PW;
    size_t rb = (size_t)(b*PW + row);
    if (row == 0 || row == 257 || col == 0 || col == 257){
      #pragma unroll
      for (int g=0; g<4; g++){
        size_t a = (rb*4+g)*RHH + (size_t)col*8;
        *(uint2*)(HH0+a) = (uint2){0,0};
        *(uint2*)(HH1+a) = (uint2){0,0};
      }
      #pragma unroll
      for (int h=0; h<2; h++){
        size_t a = (rb*2+h)*RTT + (size_t)col*16;
        *(uint4*)(TAIL0+a) = (uint4){0,0,0,0};
        *(uint4*)(TAIL1+a) = (uint4){0,0,0,0};
      }
    } else {
      int y = row-1, xc = col-1;
      int rem = (y<<8) + xc;
      const float* xb = x + (size_t)b*6*HW2D;
      float wall = xb[rem];
      float fre = 1.0f - wall;
      float s_r = xb[HW2D + rem]*fre;
      float s_i = xb[2*HW2D + rem]*fre;
      WALL[b*HW2D + rem] = wall;
      float src10[10];
      src10[0]=wall;
      #pragma unroll
      for (int c=1;c<6;c++) src10[c]=xb[c*HW2D+rem];
      src10[6]=s_r; src10[7]=s_i; src10[8]=s_r; src10[9]=s_i;
      float hv[32];
      #pragma unroll
      for (int c=0;c<32;c++){
        float a = b_in[c];
        #pragma unroll
        for (int k=0;k<10;k++) a += w_in[c*10+k]*src10[k];
        hv[c] = tanh_a(a)*fre;
      }
      // record byte 4w+t: ch {2w, 16+2w, 2w+1, 17+2w}; plane g = words 2g,2g+1
      unsigned int words[8];
      #pragma unroll
      for (int w=0;w<8;w++){
        int lo = __builtin_amdgcn_cvt_pk_fp8_f32(hv[2*w], hv[16+2*w], 0, false);
        words[w] = (unsigned int)__builtin_amdgcn_cvt_pk_fp8_f32(hv[2*w+1], hv[17+2*w], lo, true);
      }
      #pragma unroll
      for (int g=0; g<4; g++){
        *(uint2*)(HH0 + (rb*4+g)*RHH + (size_t)col*8) = (uint2){words[2*g], words[2*g+1]};
      }
      unsigned short tv[16];
      tv[0]=f2bfu(s_r); tv[1]=f2bfu(s_i); tv[2]=f2bfu(s_r); tv[3]=f2bfu(s_i);
      #pragma unroll
      for (int c=0;c<6;c++) tv[4+c] = f2bfu(src10[c]);
      #pragma unroll
      for (int c=10;c<16;c++) tv[c] = 0;
      #pragma unroll
      for (int h=0; h<2; h++){
        short8 vv;
        #pragma unroll
        for (int j=0;j<8;j++) vv[j] = (short)tv[h*8+j];
        *(short8*)(TAIL0 + (rb*2+h)*RTT + (size_t)col*16) = vv;
        *(short8*)(TAIL1 + (rb*2+h)*RTT + (size_t)col*16) = vv;
      }
      v = __builtin_amdgcn_sqrtf(s_r*s_r + s_i*s_i);
    }
  }
  #pragma unroll
  for (int off=32; off>0; off>>=1) v += __shfl_down(v, off);
  if ((tid&63)==0 && v != 0.0f)
    atomicAdd(&ST[(blockIdx.x & 63)*32 + 16], v);
}

// Fused step, barrier-free: conv (MFMA, setprio-wrapped) -> gate via shuffle ->
// epilogue stores -> phase B from TAIL(bf16) -> per-wave stat atomics.
// step==16 additionally computes sat/leak in-register (k_tail fused away).
__global__ __launch_bounds__(256) void k_step(
    const unsigned char* __restrict__ HHo, unsigned char* __restrict__ HHn,
    const unsigned char* __restrict__ TAILo, unsigned char* __restrict__ TAILn,
    const float* __restrict__ WALL,
    const u64* __restrict__ WB8, const short8* __restrict__ WB16,
    const float* __restrict__ b_up, const float* __restrict__ x,
    const float* __restrict__ b_gate, const float* __restrict__ PRM,
    float* ST, int step){
  int bid = blockIdx.x;
  int b = bid & 7, y = bid >> 3;
  int tid = threadIdx.x;
  int wv = tid >> 6, lane = tid & 63;
  int r_ = lane & 15, g = lane >> 4;
  int px0 = wv*64 + r_;

  // ---- phase-B loads from TAILo (zero-padded -> branch-free stencil) ----
  const unsigned char* Tc = TAILo + (size_t)(b*PW + y + 1)*ROWB + (size_t)(tid+1)*16;
  unsigned int sw  = *(const unsigned int*)(Tc);            // s_r,s_i (bf16 pair)
  unsigned int fu  = *(const unsigned int*)(Tc - ROWB + 4); // f_r,f_i neighbors
  unsigned int fd  = *(const unsigned int*)(Tc + ROWB + 4);
  unsigned int fl  = *(const unsigned int*)(Tc - 16 + 4);
  unsigned int fr2 = *(const unsigned int*)(Tc + 16 + 4);
  float dlr = 0.f, dli = 0.f;
  if (step==8){
    const float* xb = x + (size_t)b*6*HW2D;
    int rem = (y<<8)+tid;
    dlr = xb[3*HW2D+rem]; dli = xb[4*HW2D+rem];
  }
  float wallB = WALL[b*HW2D + (y<<8) + tid];
  float ca = PRM[0], sa = PRM[1], dec = PRM[2];

  // ---- per-thread base pointers (conv loads = base + const imm) ----
  const unsigned char* Hrow = HHo + (size_t)(b*PW + y)*ROWB + (size_t)g*RHH + (size_t)px0*8;
  const unsigned char* Trow = TAILo + (size_t)(b*PW + y)*ROWB + (size_t)(g&1)*RTT + (size_t)px0*16;
  const unsigned char* Tzero = TAILo + (size_t)(b*PW)*ROWB + (size_t)(g&1)*RTT + (size_t)px0*16;
  int gb = g >> 1;
  const unsigned char* tb0 = Trow + (size_t)((0+gb)/3)*ROWB + (size_t)((0+gb)%3)*16;
  const unsigned char* tb1 = Trow + (size_t)((2+gb)/3)*ROWB + (size_t)((2+gb)%3)*16;
  const unsigned char* tb2 = Trow + (size_t)((4+gb)/3)*ROWB + (size_t)((4+gb)%3)*16;
  const unsigned char* tb3 = Trow + (size_t)((6+gb)/3)*ROWB + (size_t)((6+gb)%3)*16;
  const unsigned char* tb4 = gb ? Tzero : (Trow + 2*ROWB + 2*16);  // tap 8 or zero tap 9
  const u64* wb8l = WB8 + lane;
  const short8* wb16l = WB16 + lane;

  f32x4 acc[4][2], accg[4];
  #pragma unroll
  for (int mt=0;mt<4;mt++){
    acc[mt][0] = (f32x4){0.f,0.f,0.f,0.f};
    acc[mt][1] = (f32x4){0.f,0.f,0.f,0.f};
    accg[mt]   = (f32x4){0.f,0.f,0.f,0.f};
  }

  __builtin_amdgcn_s_setprio(1);
  // seg1: 9 taps x 32 hh channels, fp8
  #pragma unroll
  for (int s=0;s<9;s++){
    u64 b0 = wb8l[s*64], b1 = wb8l[(9+s)*64];
    u64 aH[4];
    #pragma unroll
    for (int mt=0;mt<4;mt++)
      aH[mt] = *(const u64*)(Hrow + (size_t)((s/3)*ROWB) + ((s%3)*8 + mt*128));
    #pragma unroll
    for (int mt=0;mt<4;mt++){
      acc[mt][0] = __builtin_amdgcn_mfma_f32_16x16x32_fp8_fp8((long)b0, (long)aH[mt], acc[mt][0], 0,0,0);
      acc[mt][1] = __builtin_amdgcn_mfma_f32_16x16x32_fp8_fp8((long)b1, (long)aH[mt], acc[mt][1], 0,0,0);
    }
    if (s==4){
      u64 bg = wb8l[18*64];
      #pragma unroll
      for (int mt=0;mt<4;mt++)
        accg[mt] = __builtin_amdgcn_mfma_f32_16x16x32_fp8_fp8((long)bg, (long)aH[mt], accg[mt], 0,0,0);
    }
  }
  // seg2: 5 pair-steps x 16 tail channels, bf16
  #pragma unroll
  for (int s2=0;s2<5;s2++){
    short8 b0 = wb16l[s2*64], b1 = wb16l[(5+s2)*64];
    const unsigned char* tb = (s2==0)?tb0:(s2==1)?tb1:(s2==2)?tb2:(s2==3)?tb3:tb4;
    short8 aT[4];
    #pragma unroll
    for (int mt=0;mt<4;mt++)
      aT[mt] = *(const short8*)(tb + mt*256);
    #pragma unroll
    for (int mt=0;mt<4;mt++){
      acc[mt][0] = __builtin_amdgcn_mfma_f32_16x16x32_bf16(b0, aT[mt], acc[mt][0], 0,0,0);
      acc[mt][1] = __builtin_amdgcn_mfma_f32_16x16x32_bf16(b1, aT[mt], acc[mt][1], 0,0,0);
    }
    if (s2==2){
      short8 bgt = wb16l[10*64];
      #pragma unroll
      for (int mt=0;mt<4;mt++)
        accg[mt] = __builtin_amdgcn_mfma_f32_16x16x32_bf16(bgt, aT[mt], accg[mt], 0,0,0);
    }
  }
  __builtin_amdgcn_s_setprio(0);

  // gate redistribution, intra-wave: D row 0 = lanes 0-15 reg 0 of each mt.
  // thread's pixel (lane) = mt*16 + r_ with mt = g -> pull from lane r_.
  float ga0 = __shfl(accg[0][0], r_);
  float ga1 = __shfl(accg[1][0], r_);
  float ga2 = __shfl(accg[2][0], r_);
  float ga3 = __shfl(accg[3][0], r_);
  float gpre = (g==0) ? ga0 : (g==1) ? ga1 : (g==2) ? ga2 : ga3;

  // ---- epilogue: hh_new = tanh_a(acc + bias)*free, coalesced plane-g stores ----
  const float* wallrow = WALL + (size_t)b*HW2D + (y<<8);
  const float4* bup4 = (const float4*)b_up;
  float4 bb0 = bup4[g];
  float4 bb1 = bup4[4+g];
  unsigned char* Hn = HHn + ((size_t)(b*PW + y + 1)*4 + g)*RHH;
  #pragma unroll
  for (int mt=0;mt<4;mt++){
    int px = px0 + mt*16;
    float fre = 1.0f - wallrow[px];
    float tA0 = tanh_a(acc[mt][0][0] + bb0.x)*fre;
    float tB0 = tanh_a(acc[mt][1][0] + bb1.x)*fre;
    float tA1 = tanh_a(acc[mt][0][1] + bb0.y)*fre;
    float tB1 = tanh_a(acc[mt][1][1] + bb1.y)*fre;
    float tA2 = tanh_a(acc[mt][0][2] + bb0.z)*fre;
    float tB2 = tanh_a(acc[mt][1][2] + bb1.z)*fre;
    float tA3 = tanh_a(acc[mt][0][3] + bb0.w)*fre;
    float tB3 = tanh_a(acc[mt][1][3] + bb1.w)*fre;
    int w0 = __builtin_amdgcn_cvt_pk_fp8_f32(tA0, tB0, 0, false);
    w0 = __builtin_amdgcn_cvt_pk_fp8_f32(tA1, tB1, w0, true);
    int w1 = __builtin_amdgcn_cvt_pk_fp8_f32(tA2, tB2, 0, false);
    w1 = __builtin_amdgcn_cvt_pk_fp8_f32(tA3, tB3, w1, true);
    *(uint2*)(Hn + (size_t)(px+1)*8) = (uint2){(unsigned)w0, (unsigned)w1};
  }

  // ---- phase B (no barrier; all inputs are wave-local) ----
  float s_r = blo(sw), s_i = bhi(sw);
  float incr = blo(fu) + blo(fd) + blo(fl) + blo(fr2) + dlr;
  float inci = bhi(fu) + bhi(fd) + bhi(fl) + bhi(fr2) + dli;
  float fre = 1.0f - wallB;
  float a = gpre + b_gate[0];
  float gg = 0.998f + 0.002f*fast_sigmoid(a);
  incr *= gg; inci *= gg;
  float rr = incr*ca - inci*sa;
  float ri = incr*sa + inci*ca;
  incr = rr*fre; inci = ri*fre;
  float m1 = fmaf(incr,incr, fmaf(inci,inci, 1e-8f));
  float sc2 = fminf(2.0f*__builtin_amdgcn_rsqf(m1), 1.0f);
  incr *= sc2; inci *= sc2;
  float pw = (fabsf(incr)+fabsf(inci))*wallB;
  float nr = dec*s_r + incr, ni = dec*s_i + inci;
  float m2 = fmaf(nr,nr, fmaf(ni,ni, 1e-8f));
  sc2 = fminf(2.0f*__builtin_amdgcn_rsqf(m2), 1.0f);
  nr = nr*sc2*fre; ni = ni*sc2*fre;
  // TAIL write: row y+1, col tid+1, half 0, first 8 B = {s_r,s_i,f_r,f_i}
  ushort4 pk;
  pk.x = f2bfu(nr); pk.y = f2bfu(ni); pk.z = f2bfu(incr); pk.w = f2bfu(inci);
  *(ushort4*)(TAILn + (size_t)(b*PW + y + 1)*ROWB + (size_t)(tid+1)*16) = pk;
  float d2 = (nr-s_r)*(nr-s_r)+(ni-s_i)*(ni-s_i);
  float nrm = __builtin_amdgcn_sqrtf(nr*nr+ni*ni);
  #pragma unroll
  for (int off=32; off>0; off>>=1){
    d2  += __shfl_down(d2, off);
    nrm += __shfl_down(nrm, off);
    pw  += __shfl_down(pw, off);
  }
  if (step==16){
    // fused k_tail: sat/leak on final state (in-register, pre-rounding)
    float sat = (fabsf(nr)>4.0f ? 1.0f:0.0f) + (fabsf(ni)>4.0f ? 1.0f:0.0f);
    float nn = __builtin_amdgcn_sqrtf(nr*nr+ni*ni);
    float leak = (nn>0.5f && wallB>0.5f) ? 1.0f : 0.0f;
    #pragma unroll
    for (int off=32; off>0; off>>=1){
      sat  += __shfl_down(sat, off);
      leak += __shfl_down(leak, off);
    }
    if (lane==0){
      float* st = ST + ((bid*4+wv) & 63)*32;
      atomicAdd(&st[18], sat);
      atomicAdd(&st[19], leak);
    }
  }
  if (lane==0){
    float* st = ST + ((bid*4+wv) & 63)*32;
    atomicAdd(&st[step-1], d2);
    atomicAdd(&st[16],     nrm);
    atomicAdd(&st[17],     pw);
  }
}

__global__ void k_final(const unsigned char* __restrict__ TAIL, const int* __restrict__ target,
                        const float* __restrict__ ST, float* __restrict__ out){
  int t = threadIdx.x;   // 64 threads = one wave
  if (t < 8){
    int ty = target[2*t], tx = target[2*t+1];
    unsigned int sw = *(const unsigned int*)(TAIL + (size_t)(t*PW+ty+1)*ROWB + (size_t)(tx+1)*16);
    float vr = blo(sw), vi = bhi(sw);
    float mag = sqrtf(vr*vr+vi*vi+1e-8f);
    out[t*9] = (0.35f - mag)*12.0f;
    #pragma unroll
    for (int k=0;k<8;k++){
      float th = 6.283185307179586f * (float)k / 8.0f;
      out[t*9+1+k] = (vr*cosf(th)+vi*sinf(th) - 0.35f)*12.0f;
    }
  }
  // reduce ST[64][32] across slots (all 64 lanes participate)
  float tot[20];
  #pragma unroll
  for (int i=0;i<20;i++){
    float v = ST[t*32 + i];
    #pragma unroll
    for (int off=32; off>0; off>>=1) v += __shfl_down(v, off);
    tot[i] = v;   // valid on lane 0
  }
  if (t == 0){
    float d = 0.0f;
    #pragma unroll
    for (int s=0;s<16;s++) d += sqrtf(tot[s]/1048576.0f);
    out[72] = d/16.0f;
    out[73] = tot[16]/8912896.0f;
    out[74] = tot[18]/1048576.0f;
    out[75] = tot[17]/(524288.0f*16.0f);
    out[76] = tot[19]/524288.0f;
  }
}

extern "C" void kernel_launch(void* const* d_in, const int* in_sizes, int n_in,
                              void* d_out, int out_size, void* d_ws, size_t ws_size,
                              hipStream_t stream) {
  const float* x       = (const float*)d_in[0];
  const int*   target  = (const int*)  d_in[1];
  const float* w_in    = (const float*)d_in[2];
  const float* b_in    = (const float*)d_in[3];
  const float* w_up    = (const float*)d_in[4];
  const float* b_up    = (const float*)d_in[5];
  const float* w_gate  = (const float*)d_in[6];
  const float* b_gate  = (const float*)d_in[7];
  const float* angle   = (const float*)d_in[8];
  const float* decay_l = (const float*)d_in[9];
  float* out = (float*)d_out;

  char* ws = (char*)d_ws;
  size_t off = 0;
  unsigned char* HH0 = (unsigned char*)(ws+off); off += (size_t)NB*PP*32;
  unsigned char* HH1 = (unsigned char*)(ws+off); off += (size_t)NB*PP*32;
  unsigned char* TAIL0=(unsigned char*)(ws+off); off += (size_t)NB*PP*32;
  unsigned char* TAIL1=(unsigned char*)(ws+off); off += (size_t)NB*PP*32;
  float* WALL = (float*)(ws+off); off += (size_t)NPIX*4;
  u64* WB8 = (u64*)(ws+off); off += (size_t)19*64*8;
  short8* WB16 = (short8*)(ws+off); off += (size_t)11*64*16;
  float* ST = (float*)(ws+off); off += (size_t)64*32*4;
  float* PRM = (float*)(ws+off); off += 16*4;

  k_setup<<<1,256,0,stream>>>(w_up, w_gate, angle, decay_l, WB8, WB16, ST, PRM);
  k_init<<<(NB*PP+255)/256,256,0,stream>>>(x, w_in, b_in, WALL, HH0, HH1,
                                           TAIL0, TAIL1, ST);

  unsigned char *hho=HH0, *hhn=HH1, *tlo=TAIL0, *tln=TAIL1;
  for (int t=1;t<=NSTEPS;t++){
    k_step<<<2048,256,0,stream>>>(hho, hhn, tlo, tln, WALL,
                                  WB8, WB16, b_up, x, b_gate, PRM, ST, t);
    unsigned char* tc=hho; hho=hhn; hhn=tc;
    tc=tlo; tlo=tln; tln=tc;
  }
  k_final<<<1,64,0,stream>>>(tlo, target, ST, out);
}